// Round 2
// baseline (321.926 us; speedup 1.0000x reference)
//
#include <hip/hip_runtime.h>

typedef short short8 __attribute__((ext_vector_type(8)));
typedef short short4v __attribute__((ext_vector_type(4)));
typedef float f32x4 __attribute__((ext_vector_type(4)));
typedef unsigned short u16;

__device__ __forceinline__ u16 f2bf(float f) {
  unsigned int u = __builtin_bit_cast(unsigned int, f);
  u = (u + 0x7FFFu + ((u >> 16) & 1u)) >> 16;
  return (u16)u;
}
__device__ __forceinline__ float bf2f(u16 h) {
  unsigned int u = ((unsigned int)h) << 16;
  return __builtin_bit_cast(float, u);
}
__device__ __forceinline__ short8 cvt8(float4 a, float4 b) {
  short8 v;
  v[0] = (short)f2bf(a.x); v[1] = (short)f2bf(a.y);
  v[2] = (short)f2bf(a.z); v[3] = (short)f2bf(a.w);
  v[4] = (short)f2bf(b.x); v[5] = (short)f2bf(b.y);
  v[6] = (short)f2bf(b.z); v[7] = (short)f2bf(b.w);
  return v;
}
__device__ __forceinline__ short4v pack4(f32x4 a) {
  short4v v;
  v[0] = (short)f2bf(a[0]); v[1] = (short)f2bf(a[1]);
  v[2] = (short)f2bf(a[2]); v[3] = (short)f2bf(a[3]);
  return v;
}
__device__ __forceinline__ float sigmoidf_fast(float x) {
  return __builtin_amdgcn_rcpf(1.0f + __expf(-x));
}
__device__ __forceinline__ float tanhf_fast(float x) {
  return 1.0f - 2.0f * __builtin_amdgcn_rcpf(1.0f + __expf(2.0f * x));
}

// ---------------------------------------------------------------------------
// K1: xg[px][768] = x[px][192] @ W4^T + (bih+bhh), bf16 out.
// 256 blocks x 8 waves. Wave w: dir = w>>1, n-range = (w&1)*96 .. +96.
// W fragments in registers (36/wave); x tile double-buffered in LDS (12 KB).
// ---------------------------------------------------------------------------
__global__ __launch_bounds__(512, 1)
void xg_gemm_kernel(const float* __restrict__ x,
    const float* __restrict__ w0, const float* __restrict__ w1,
    const float* __restrict__ w2, const float* __restrict__ w3,
    const float* __restrict__ bi0, const float* __restrict__ bh0,
    const float* __restrict__ bi1, const float* __restrict__ bh1,
    const float* __restrict__ bi2, const float* __restrict__ bh2,
    const float* __restrict__ bi3, const float* __restrict__ bh3,
    u16* __restrict__ xg)
{
  __shared__ u16 xl[2][3072];          // [16 px][192 k] bf16, XOR-swizzled
  const int tid  = threadIdx.x;
  const int lane = tid & 63;
  const int wv   = tid >> 6;           // 0..7
  const int cl   = lane & 15;
  const int kg   = lane >> 4;
  const int dir  = wv >> 1;
  const int nbase = (wv & 1) * 96;

  const float* wp  = dir == 0 ? w0 : dir == 1 ? w1 : dir == 2 ? w2 : w3;
  const float* bip = dir == 0 ? bi0 : dir == 1 ? bi1 : dir == 2 ? bi2 : bi3;
  const float* bhp = dir == 0 ? bh0 : dir == 1 ? bh1 : dir == 2 ? bh2 : bh3;

  // W fragments: A-operand, row n = nbase+nt*16+cl, k = kk*32+kg*8+j
  short8 wf[6][6];
  #pragma unroll
  for (int nt = 0; nt < 6; ++nt) {
    int n = nbase + nt * 16 + cl;
    #pragma unroll
    for (int kk = 0; kk < 6; ++kk) {
      const float4* p = (const float4*)(wp + n * 192 + kk * 32 + kg * 8);
      wf[nt][kk] = cvt8(p[0], p[1]);
    }
  }
  // bias folded into acc-init; D rows n = nbase + nt*16 + kg*4 + r
  f32x4 bv[6];
  #pragma unroll
  for (int nt = 0; nt < 6; ++nt)
    #pragma unroll
    for (int r = 0; r < 4; ++r) {
      int n = nbase + nt * 16 + kg * 4 + r;
      bv[nt][r] = bip[n] + bhp[n];
    }

  const int spx = tid / 24;            // staging: tid<384 -> (px, k0)
  const int sk  = (tid % 24) * 8;
  float4 sa, sb;

  auto sload = [&](int it) {
    if (tid < 384) {
      const float4* p = (const float4*)(x + (size_t)((blockIdx.x * 36 + it) * 16 + spx) * 192 + sk);
      sa = p[0]; sb = p[1];
    }
  };
  auto swrite = [&](int b) {
    if (tid < 384) {
      int idx = (spx * 192 + sk) ^ ((spx & 7) << 3);
      *(short8*)&xl[b][idx] = cvt8(sa, sb);
    }
  };

  sload(0); swrite(0); __syncthreads();

  int buf = 0;
  for (int it = 0; it < 36; ++it) {
    if (it < 35) sload(it + 1);        // in-flight during compute
    const int pxb = (blockIdx.x * 36 + it) * 16;

    f32x4 acc[6];
    #pragma unroll
    for (int nt = 0; nt < 6; ++nt) acc[nt] = bv[nt];
    #pragma unroll
    for (int kk = 0; kk < 6; ++kk) {
      int idx = (cl * 192 + kk * 32 + kg * 8) ^ ((cl & 7) << 3);
      short8 bfr = *(const short8*)&xl[buf][idx];
      #pragma unroll
      for (int nt = 0; nt < 6; ++nt)
        acc[nt] = __builtin_amdgcn_mfma_f32_16x16x32_bf16(wf[nt][kk], bfr, acc[nt], 0, 0, 0);
    }
    #pragma unroll
    for (int nt = 0; nt < 6; ++nt) {
      size_t o = (size_t)(pxb + cl) * 768 + dir * 192 + nbase + nt * 16 + kg * 4;
      *(short4v*)(xg + o) = pack4(acc[nt]);
    }
    __syncthreads();
    if (it < 35) swrite(buf ^ 1);
    __syncthreads();
    buf ^= 1;
  }
}

// ---------------------------------------------------------------------------
// K2: recurrent scan. 192 blocks x 4 waves; each wave autonomous (no barriers),
// owns 16 sequences of one direction. whh in registers, h via wave-private LDS,
// xg streamed with 1-step register prefetch. acc-init = xg (bias prefolded).
// ---------------------------------------------------------------------------
__global__ __launch_bounds__(256, 1)
void scan_kernel(const u16* __restrict__ xg,
    const float* __restrict__ u0, const float* __restrict__ u1,
    const float* __restrict__ u2, const float* __restrict__ u3,
    u16* __restrict__ comb)
{
  __shared__ u16 hl[4][16 * 72];       // per-wave [16 seq][72] (48 h + 24 zero pad)
  const int tid  = threadIdx.x;
  const int lane = tid & 63;
  const int wv   = tid >> 6;
  const int cl   = lane & 15;
  const int kg   = lane >> 4;
  const int W    = blockIdx.x * 4 + wv;  // 0..767
  const int dir  = W / 192;
  const int g    = W - dir * 192;
  const int bb   = g / 3;
  const int rc   = (g - bb * 3) * 16 + cl;
  const bool vert = dir < 2;
  const bool bwd  = (dir & 1) != 0;

  const float* up = dir == 0 ? u0 : dir == 1 ? u1 : dir == 2 ? u2 : u3;

  // whh fragments (A-operand), K padded 48->64; zero for k>=48
  short8 uf[12][2];
  #pragma unroll
  for (int nt = 0; nt < 12; ++nt) {
    int n = nt * 16 + cl;
    {
      const float4* p = (const float4*)(up + n * 48 + kg * 8);
      uf[nt][0] = cvt8(p[0], p[1]);
    }
    if (kg < 2) {
      const float4* p = (const float4*)(up + n * 48 + 32 + kg * 8);
      uf[nt][1] = cvt8(p[0], p[1]);
    } else {
      short8 z = {}; uf[nt][1] = z;
    }
  }

  // zero this wave's h strip (incl. pad) -> t=0 sees h=0
  u16* hrow = &hl[wv][0];
  for (int i = 0; i < 18; ++i) hrow[lane * 18 + i] = 0;

  float c[12];
  #pragma unroll
  for (int i = 0; i < 12; ++i) c[i] = 0.f;

  const int tp0 = bwd ? 47 : 0;
  int px = vert ? (bb * 48 + tp0) * 48 + rc : (bb * 48 + rc) * 48 + tp0;
  const int dpx = (vert ? 48 : 1) * (bwd ? -1 : 1);

  // prefetch xg for t=0
  short4v xb[12];
  {
    const u16* xp = xg + (size_t)px * 768 + dir * 192 + kg * 4;
    #pragma unroll
    for (int nt = 0; nt < 12; ++nt)
      xb[nt] = *(const short4v*)(xp + nt * 16);
  }

  for (int t = 0; t < 48; ++t) {
    // h B-fragments: lane (cl,kg) reads h[seq=cl][k=kg*8..+8]
    short8 hb0 = *(const short8*)&hl[wv][cl * 72 + kg * 8];
    short8 hb1 = *(const short8*)&hl[wv][cl * 72 + 32 + kg * 8]; // zeros for kg>=2

    f32x4 acc[12];
    #pragma unroll
    for (int nt = 0; nt < 12; ++nt) {
      f32x4 a;
      a[0] = bf2f((u16)xb[nt][0]); a[1] = bf2f((u16)xb[nt][1]);
      a[2] = bf2f((u16)xb[nt][2]); a[3] = bf2f((u16)xb[nt][3]);
      acc[nt] = a;
    }
    #pragma unroll
    for (int nt = 0; nt < 12; ++nt)
      acc[nt] = __builtin_amdgcn_mfma_f32_16x16x32_bf16(uf[nt][0], hb0, acc[nt], 0, 0, 0);
    #pragma unroll
    for (int nt = 0; nt < 12; ++nt)
      acc[nt] = __builtin_amdgcn_mfma_f32_16x16x32_bf16(uf[nt][1], hb1, acc[nt], 0, 0, 0);

    // prefetch next step's xg while epilogue runs
    int pxn = px + dpx;
    if (t < 47) {
      const u16* xp = xg + (size_t)pxn * 768 + dir * 192 + kg * 4;
      #pragma unroll
      for (int nt = 0; nt < 12; ++nt)
        xb[nt] = *(const short4v*)(xp + nt * 16);
    }

    // epilogue: lane holds i,f,g,o for seq=cl, hd = 16q + 4kg + r
    #pragma unroll
    for (int q = 0; q < 3; ++q) {
      short4v h4;
      #pragma unroll
      for (int r = 0; r < 4; ++r) {
        float xi  = acc[q][r];
        float xf  = acc[3 + q][r];
        float xgv = acc[6 + q][r];
        float xo  = acc[9 + q][r];
        float ii = sigmoidf_fast(xi);
        float ff = sigmoidf_fast(xf);
        float gg = tanhf_fast(xgv);
        float oo = sigmoidf_fast(xo);
        float cc = ff * c[q * 4 + r] + ii * gg;
        c[q * 4 + r] = cc;
        float hh = oo * tanhf_fast(cc);
        h4[r] = (short)f2bf(hh);
      }
      *(short4v*)&hl[wv][cl * 72 + q * 16 + kg * 4] = h4;
      *(short4v*)&comb[(size_t)px * 192 + dir * 48 + q * 16 + kg * 4] = h4;
    }
    px = pxn;
  }
}

// ---------------------------------------------------------------------------
// K3: out[p][c] = comb[p][:] @ proj_w[c][:] + proj_b[c]   (unchanged)
// ---------------------------------------------------------------------------
__global__ __launch_bounds__(256, 1)
void proj_kernel(const u16* __restrict__ comb,
                 const float* __restrict__ pw,
                 const float* __restrict__ pb,
                 float* __restrict__ out)
{
  __shared__ u16 lds[49152];
  u16* Alds = lds;                     // [64][192] bf16, swizzled
  u16* Blds = lds + 12288;             // [192][192] bf16, swizzled

  const int tid = threadIdx.x;
  const int lane = tid & 63;
  const int wv = tid >> 6;
  const int cl = lane & 15;
  const int kg = lane >> 4;
  const size_t p0 = (size_t)blockIdx.x * 64;

  for (int i = 0; i < 18; ++i) {
    int ch = tid + 256 * i;
    int n  = ch / 24;
    int k0 = (ch % 24) << 3;
    const float4* s0 = (const float4*)(pw + n * 192 + k0);
    *(short8*)(&Blds[(n * 192 + k0) ^ ((n & 7) << 3)]) = cvt8(s0[0], s0[1]);
  }
  for (int i = 0; i < 6; ++i) {
    int ch = tid + 256 * i;
    int s  = ch / 24;
    int k0 = (ch % 24) << 3;
    short8 v = *(const short8*)(comb + (p0 + s) * 192 + k0);
    *(short8*)(&Alds[(s * 192 + k0) ^ ((s & 7) << 3)]) = v;
  }
  float pbr[3];
  #pragma unroll
  for (int ni = 0; ni < 3; ++ni) pbr[ni] = pb[wv * 48 + ni * 16 + cl];

  __syncthreads();

  f32x4 acc[4][3] = {};
  #pragma unroll
  for (int kk = 0; kk < 6; ++kk) {
    int krow = kk * 32 + kg * 8;
    short8 af[4], bf[3];
    #pragma unroll
    for (int mi = 0; mi < 4; ++mi) {
      int row = mi * 16 + cl;
      af[mi] = *(const short8*)(&Alds[(row * 192 + krow) ^ ((row & 7) << 3)]);
    }
    #pragma unroll
    for (int ni = 0; ni < 3; ++ni) {
      int col = wv * 48 + ni * 16 + cl;
      bf[ni] = *(const short8*)(&Blds[(col * 192 + krow) ^ ((col & 7) << 3)]);
    }
    #pragma unroll
    for (int mi = 0; mi < 4; ++mi)
      #pragma unroll
      for (int ni = 0; ni < 3; ++ni)
        acc[mi][ni] = __builtin_amdgcn_mfma_f32_16x16x32_bf16(
            af[mi], bf[ni], acc[mi][ni], 0, 0, 0);
  }

  #pragma unroll
  for (int mi = 0; mi < 4; ++mi)
    #pragma unroll
    for (int ni = 0; ni < 3; ++ni)
      #pragma unroll
      for (int r = 0; r < 4; ++r) {
        size_t o = (p0 + mi * 16 + kg * 4 + r) * 192 + wv * 48 + ni * 16 + cl;
        out[o] = acc[mi][ni][r] + pbr[ni];
      }
}

extern "C" void kernel_launch(void* const* d_in, const int* in_sizes, int n_in,
                              void* d_out, int out_size, void* d_ws, size_t ws_size,
                              hipStream_t stream) {
  const float* x = (const float*)d_in[0];
  u16* xg   = (u16*)d_ws;                                // 147456*768*2B = 226.5 MB
  u16* comb = (u16*)d_ws + (size_t)147456 * 768;         // + 56.6 MB

  xg_gemm_kernel<<<256, 512, 0, stream>>>(
      x,
      (const float*)d_in[1], (const float*)d_in[5],
      (const float*)d_in[9], (const float*)d_in[13],
      (const float*)d_in[3],  (const float*)d_in[4],
      (const float*)d_in[7],  (const float*)d_in[8],
      (const float*)d_in[11], (const float*)d_in[12],
      (const float*)d_in[15], (const float*)d_in[16],
      xg);

  scan_kernel<<<192, 256, 0, stream>>>(
      xg,
      (const float*)d_in[2], (const float*)d_in[6],
      (const float*)d_in[10], (const float*)d_in[14],
      comb);

  proj_kernel<<<2304, 256, 0, stream>>>(
      comb, (const float*)d_in[17], (const float*)d_in[18], (float*)d_out);
}